// Round 1
// baseline (210.109 us; speedup 1.0000x reference)
//
#include <hip/hip_runtime.h>
#include <math.h>

// ---------------- problem constants ----------------
namespace {
constexpr int Bn = 4, Sn = 8, Cn = 3, Himg = 256, Wimg = 256;
constexpr int Pn = 68, DS = 4, WIN = 8, STEPS = 10;
constexpr int HWi = Himg * Wimg;            // 65536
constexpr int NIMG = Bn * Sn;               // 32
constexpr int HD = Himg / DS, WD = Wimg / DS; // 64 x 64
constexpr int Kwin = (2 * WIN + 1) * (2 * WIN + 1); // 289
}

// ---------------- gray conversion ----------------
__global__ __launch_bounds__(256) void gray_kernel(const float* __restrict__ in,
                                                   float* __restrict__ gray) {
    int idx = blockIdx.x * blockDim.x + threadIdx.x;   // float4 index
    int total = NIMG * HWi / 4;
    if (idx >= total) return;
    int img = idx / (HWi / 4);
    int off = idx % (HWi / 4);
    const float* base = in + (size_t)img * 3 * HWi;
    float4 c0 = ((const float4*)(base))[off];
    float4 c1 = ((const float4*)(base + HWi))[off];
    float4 c2 = ((const float4*)(base + 2 * HWi))[off];
    float4 g;
    g.x = 0.299f * c0.x + 0.587f * c1.x + 0.114f * c2.x;
    g.y = 0.299f * c0.y + 0.587f * c1.y + 0.114f * c2.y;
    g.z = 0.299f * c0.z + 0.587f * c1.z + 0.114f * c2.z;
    g.w = 0.299f * c0.w + 0.587f * c1.w + 0.114f * c2.w;
    ((float4*)(gray + (size_t)img * HWi))[off] = g;
}

// ---------------- detector conv (3x3, stride 4, pad 0 == SAME here) ----------------
__global__ __launch_bounds__(256) void conv_kernel(const float* __restrict__ x,
                                                   const float* __restrict__ Wdet,
                                                   const float* __restrict__ bdet,
                                                   float* __restrict__ hm) {
    __shared__ float wsh[Pn * 27];
    __shared__ float bsh[Pn];
    __shared__ float insh[3][3][Wimg];
    int n = blockIdx.x >> 6;
    int oy = blockIdx.x & 63;
    int tid = threadIdx.x;
    for (int t = tid; t < Pn * 27; t += 256) wsh[t] = Wdet[t];
    if (tid < Pn) bsh[tid] = bdet[tid];
    for (int t = tid; t < 3 * 3 * Wimg; t += 256) {
        int c = t / (3 * Wimg);
        int r = (t / Wimg) % 3;
        int col = t % Wimg;
        insh[c][r][col] = x[(size_t)n * 3 * HWi + (size_t)c * HWi + (oy * 4 + r) * Wimg + col];
    }
    __syncthreads();
    int ox = tid & 63;
    int wid = tid >> 6;
    // each thread: fixed ox, loads its 27 input values once into registers
    float in_reg[27];
    #pragma unroll
    for (int c = 0; c < 3; c++)
        #pragma unroll
        for (int ky = 0; ky < 3; ky++)
            #pragma unroll
            for (int kx = 0; kx < 3; kx++)
                in_reg[c * 9 + ky * 3 + kx] = insh[c][ky][ox * 4 + kx];
    #pragma unroll
    for (int i = 0; i < 17; i++) {
        int p = wid + i * 4;
        const float* w = &wsh[p * 27];
        float acc = bsh[p];
        #pragma unroll
        for (int j = 0; j < 27; j++) acc += w[j] * in_reg[j];
        hm[(size_t)n * Pn * 4096 + (size_t)p * 4096 + oy * 64 + ox] = acc;
    }
}

// ---------------- softmax / soft-argmax / scores ----------------
__global__ __launch_bounds__(256) void smax_kernel(const float* __restrict__ hm,
                                                   float* __restrict__ locs,
                                                   float* __restrict__ scos) {
    int row = blockIdx.x;   // n*Pn + p  == (b*S+s)*P + p
    const float4* r = (const float4*)(hm + (size_t)row * 4096);
    int tid = threadIdx.x;
    float v[16];
    #pragma unroll
    for (int j = 0; j < 4; j++) {
        float4 q = r[tid + 256 * j];
        v[4 * j + 0] = q.x; v[4 * j + 1] = q.y; v[4 * j + 2] = q.z; v[4 * j + 3] = q.w;
    }
    float m = v[0];
    #pragma unroll
    for (int i = 1; i < 16; i++) m = fmaxf(m, v[i]);
    __shared__ float redm[4];
    #pragma unroll
    for (int o = 32; o; o >>= 1) m = fmaxf(m, __shfl_xor(m, o, 64));
    int wid = tid >> 6, lane = tid & 63;
    if (lane == 0) redm[wid] = m;
    __syncthreads();
    m = fmaxf(fmaxf(redm[0], redm[1]), fmaxf(redm[2], redm[3]));
    float s = 0.f, sx = 0.f, sy = 0.f;
    #pragma unroll
    for (int j = 0; j < 4; j++) {
        #pragma unroll
        for (int q = 0; q < 4; q++) {
            int e = (tid + 256 * j) * 4 + q;
            float ev = expf(v[4 * j + q] - m);
            s += ev;
            sx += ev * (float)(e & 63);
            sy += ev * (float)(e >> 6);
        }
    }
    #pragma unroll
    for (int o = 32; o; o >>= 1) {
        s  += __shfl_xor(s, o, 64);
        sx += __shfl_xor(sx, o, 64);
        sy += __shfl_xor(sy, o, 64);
    }
    __shared__ float reds[3][4];
    if (lane == 0) { reds[0][wid] = s; reds[1][wid] = sx; reds[2][wid] = sy; }
    __syncthreads();
    if (tid == 0) {
        float S_ = reds[0][0] + reds[0][1] + reds[0][2] + reds[0][3];
        float SX = reds[1][0] + reds[1][1] + reds[1][2] + reds[1][3];
        float SY = reds[2][0] + reds[2][1] + reds[2][2] + reds[2][3];
        locs[(size_t)row * 2 + 0] = SX / S_ * 4.0f;
        locs[(size_t)row * 2 + 1] = SY / S_ * 4.0f;
        scos[row] = m;
    }
}

// ---------------- LK tracking ----------------
// FLY=false: img points into precomputed gray frames (stride HWi).
// FLY=true:  img points into raw input frames [C,H,W] (stride 3*HWi), gray on the fly.
template <bool FLY>
__device__ inline float px_at(const float* __restrict__ im, int y, int x) {
    int i = y * Wimg + x;
    if constexpr (FLY)
        return 0.299f * im[i] + 0.587f * im[i + HWi] + 0.114f * im[i + 2 * HWi];
    else
        return im[i];
}

template <bool FLY>
__device__ inline float bilin(const float* __restrict__ im, float x, float y) {
    const float XM = (float)(Wimg - 1.001);
    const float YM = (float)(Himg - 1.001);
    x = fminf(fmaxf(x, 0.0f), XM);
    y = fminf(fmaxf(y, 0.0f), YM);
    float x0f = floorf(x), y0f = floorf(y);
    float wx = x - x0f, wy = y - y0f;
    int x0 = (int)x0f, y0 = (int)y0f;
    int x1 = min(x0 + 1, Wimg - 1), y1 = min(y0 + 1, Himg - 1);
    float v00 = px_at<FLY>(im, y0, x0);
    float v01 = px_at<FLY>(im, y0, x1);
    float v10 = px_at<FLY>(im, y1, x0);
    float v11 = px_at<FLY>(im, y1, x1);
    return (1.0f - wy) * ((1.0f - wx) * v00 + wx * v01) + wy * ((1.0f - wx) * v10 + wx * v11);
}

// template sample: value + on-the-fly central-difference gradients (exact same math
// as bilinear-sampling the padded-gradient images of the reference)
template <bool FLY>
__device__ inline void sample_tpl(const float* __restrict__ im, float x, float y,
                                  float& I0, float& Ix, float& Iy) {
    const float XM = (float)(Wimg - 1.001);
    const float YM = (float)(Himg - 1.001);
    x = fminf(fmaxf(x, 0.0f), XM);
    y = fminf(fmaxf(y, 0.0f), YM);
    float x0f = floorf(x), y0f = floorf(y);
    float wx = x - x0f, wy = y - y0f;
    int x0 = (int)x0f, y0 = (int)y0f;
    int x1 = min(x0 + 1, Wimg - 1), y1 = min(y0 + 1, Himg - 1);
    int xm = max(x0 - 1, 0), xp = min(x1 + 1, Wimg - 1);
    int ym = max(y0 - 1, 0), yp = min(y1 + 1, Himg - 1);
    float a_m0 = px_at<FLY>(im, ym, x0), a_m1 = px_at<FLY>(im, ym, x1);
    float a_0m = px_at<FLY>(im, y0, xm), a_00 = px_at<FLY>(im, y0, x0);
    float a_01 = px_at<FLY>(im, y0, x1), a_0p = px_at<FLY>(im, y0, xp);
    float a_1m = px_at<FLY>(im, y1, xm), a_10 = px_at<FLY>(im, y1, x0);
    float a_11 = px_at<FLY>(im, y1, x1), a_1p = px_at<FLY>(im, y1, xp);
    float a_p0 = px_at<FLY>(im, yp, x0), a_p1 = px_at<FLY>(im, yp, x1);
    float u = 1.0f - wx, t = 1.0f - wy;
    I0 = t * (u * a_00 + wx * a_01) + wy * (u * a_10 + wx * a_11);
    float gx00 = 0.5f * (a_01 - a_0m);
    float gx01 = 0.5f * (a_0p - a_00);
    float gx10 = 0.5f * (a_11 - a_1m);
    float gx11 = 0.5f * (a_1p - a_10);
    Ix = t * (u * gx00 + wx * gx01) + wy * (u * gx10 + wx * gx11);
    float gy00 = 0.5f * (a_10 - a_m0);
    float gy01 = 0.5f * (a_11 - a_m1);
    float gy10 = 0.5f * (a_p0 - a_00);
    float gy11 = 0.5f * (a_p1 - a_01);
    Iy = t * (u * gy00 + wx * gy01) + wy * (u * gy10 + wx * gy11);
}

__device__ inline float wred(float v) {
    #pragma unroll
    for (int o = 32; o; o >>= 1) v += __shfl_xor(v, o, 64);
    return v;
}

template <bool FLY>
__device__ void lk_track(const float* __restrict__ oldI, const float* __restrict__ newI,
                         float& px, float& py, const float* dxs, const float* dys,
                         int lane) {
    float I0[5], Ixa[5], Iya[5];
    float gxx = 0.f, gxy = 0.f, gyy = 0.f;
    #pragma unroll
    for (int j = 0; j < 5; j++) {
        int k = lane + 64 * j;
        float a = 0.f, b = 0.f, c = 0.f;
        if (k < Kwin) sample_tpl<FLY>(oldI, px + dxs[j], py + dys[j], a, b, c);
        I0[j] = a; Ixa[j] = b; Iya[j] = c;
        gxx += b * b; gxy += b * c; gyy += c * c;
    }
    gxx = wred(gxx); gxy = wred(gxy); gyy = wred(gyy);
    float det = gxx * gyy - gxy * gxy + 1e-6f;
    float A = gyy / det, Bv = -gxy / det, D = gxx / det;  // Ginv
    float vx = 0.f, vy = 0.f;
    for (int it = 0; it < STEPS; ++it) {
        float bx = 0.f, by = 0.f;
        #pragma unroll
        for (int j = 0; j < 5; j++) {
            int k = lane + 64 * j;
            if (k < Kwin) {
                float I1 = bilin<FLY>(newI, px + dxs[j] + vx, py + dys[j] + vy);
                float err = I0[j] - I1;
                bx += err * Ixa[j];
                by += err * Iya[j];
            }
        }
        bx = wred(bx); by = wred(by);
        vx += A * bx + Bv * by;
        vy += Bv * bx + D * by;
    }
    px += vx; py += vy;
}

template <bool FLY>
__global__ __launch_bounds__(64) void lk_kernel(const float* __restrict__ grayOrIn,
                                                const float* __restrict__ locs,
                                                float* __restrict__ nextPts,
                                                float* __restrict__ fbackPts,
                                                float* __restrict__ backPts) {
    constexpr size_t FS = FLY ? (size_t)3 * HWi : (size_t)HWi;  // frame stride
    int g = blockIdx.x;
    int typ = g / (Bn * Pn);
    int r = g % (Bn * Pn);
    int b = r / Pn;
    int p = r % Pn;
    int lane = threadIdx.x;
    const float* G = grayOrIn + (size_t)b * Sn * FS;
    float dxs[5], dys[5];
    #pragma unroll
    for (int j = 0; j < 5; j++) {
        int k = lane + 64 * j;
        int kk = (k < Kwin) ? k : 0;
        dxs[j] = (float)(kk % 17 - 8);
        dys[j] = (float)(kk / 17 - 8);
    }
    auto LIDX = [&](int s) { return (((size_t)b * Sn + s) * Pn + p) * 2; };
    if (typ == 0) {
        float px = locs[LIDX(0)], py = locs[LIDX(0) + 1];
        if (lane == 0) { nextPts[LIDX(0)] = px; nextPts[LIDX(0) + 1] = py; }
        for (int s = 0; s < 7; s++) {
            lk_track<FLY>(G + s * FS, G + (s + 1) * FS, px, py, dxs, dys, lane);
            if (lane == 0) { nextPts[LIDX(s + 1)] = px; nextPts[LIDX(s + 1) + 1] = py; }
        }
        if (lane == 0) { fbackPts[LIDX(7)] = px; fbackPts[LIDX(7) + 1] = py; }
        for (int i = 0; i < 7; i++) {
            lk_track<FLY>(G + (7 - i) * FS, G + (6 - i) * FS, px, py, dxs, dys, lane);
            if (lane == 0) { fbackPts[LIDX(6 - i)] = px; fbackPts[LIDX(6 - i) + 1] = py; }
        }
    } else {
        float px = locs[LIDX(7)], py = locs[LIDX(7) + 1];
        if (lane == 0) { backPts[LIDX(7)] = px; backPts[LIDX(7) + 1] = py; }
        for (int i = 0; i < 7; i++) {
            lk_track<FLY>(G + (7 - i) * FS, G + (6 - i) * FS, px, py, dxs, dys, lane);
            if (lane == 0) { backPts[LIDX(6 - i)] = px; backPts[LIDX(6 - i) + 1] = py; }
        }
    }
}

// ---------------- launch ----------------
extern "C" void kernel_launch(void* const* d_in, const int* in_sizes, int n_in,
                              void* d_out, int out_size, void* d_ws, size_t ws_size,
                              hipStream_t stream) {
    const float* inputs = (const float*)d_in[0];
    const float* Wdet = (const float*)d_in[1];
    const float* bdet = (const float*)d_in[2];
    float* out = (float*)d_out;

    const size_t N_hm = (size_t)Bn * Sn * Pn * HD * WD;   // 8,912,896
    const size_t N_pts = (size_t)Bn * Sn * Pn * 2;        // 4352
    float* hm = out;
    float* locs = out + N_hm;
    float* scos = locs + N_pts;
    float* nextPts = scos + (size_t)Bn * Sn * Pn;
    float* fbackPts = nextPts + N_pts;
    float* backPts = fbackPts + N_pts;

    conv_kernel<<<NIMG * 64, 256, 0, stream>>>(inputs, Wdet, bdet, hm);
    smax_kernel<<<NIMG * Pn, 256, 0, stream>>>(hm, locs, scos);

    const size_t gray_bytes = (size_t)NIMG * HWi * sizeof(float);  // 8.4 MB
    if (ws_size >= gray_bytes) {
        float* gray = (float*)d_ws;
        gray_kernel<<<(NIMG * HWi / 4 + 255) / 256, 256, 0, stream>>>(inputs, gray);
        lk_kernel<false><<<2 * Bn * Pn, 64, 0, stream>>>(gray, locs, nextPts, fbackPts, backPts);
    } else {
        lk_kernel<true><<<2 * Bn * Pn, 64, 0, stream>>>(inputs, locs, nextPts, fbackPts, backPts);
    }
}

// Round 2
// 189.213 us; speedup vs baseline: 1.1104x; 1.1104x over previous
//
#include <hip/hip_runtime.h>
#include <math.h>

// ---------------- problem constants ----------------
namespace {
constexpr int Bn = 4, Sn = 8, Cn = 3, Himg = 256, Wimg = 256;
constexpr int Pn = 68, DS = 4, WIN = 8, STEPS = 10;
constexpr int HWi = Himg * Wimg;            // 65536
constexpr int NIMG = Bn * Sn;               // 32
constexpr int HD = Himg / DS, WD = Wimg / DS; // 64 x 64
constexpr int Kwin = (2 * WIN + 1) * (2 * WIN + 1); // 289
}

// ---------------- gray conversion ----------------
__global__ __launch_bounds__(256) void gray_kernel(const float* __restrict__ in,
                                                   float* __restrict__ gray) {
    int idx = blockIdx.x * blockDim.x + threadIdx.x;   // float4 index
    int total = NIMG * HWi / 4;
    if (idx >= total) return;
    int img = idx / (HWi / 4);
    int off = idx % (HWi / 4);
    const float* base = in + (size_t)img * 3 * HWi;
    float4 c0 = ((const float4*)(base))[off];
    float4 c1 = ((const float4*)(base + HWi))[off];
    float4 c2 = ((const float4*)(base + 2 * HWi))[off];
    float4 g;
    g.x = 0.299f * c0.x + 0.587f * c1.x + 0.114f * c2.x;
    g.y = 0.299f * c0.y + 0.587f * c1.y + 0.114f * c2.y;
    g.z = 0.299f * c0.z + 0.587f * c1.z + 0.114f * c2.z;
    g.w = 0.299f * c0.w + 0.587f * c1.w + 0.114f * c2.w;
    ((float4*)(gray + (size_t)img * HWi))[off] = g;
}

// ---------------- detector conv (3x3, stride 4, pad 0 == SAME here) ----------------
__global__ __launch_bounds__(256) void conv_kernel(const float* __restrict__ x,
                                                   const float* __restrict__ Wdet,
                                                   const float* __restrict__ bdet,
                                                   float* __restrict__ hm) {
    __shared__ float wsh[Pn * 27];
    __shared__ float bsh[Pn];
    __shared__ float insh[3][3][Wimg];
    int n = blockIdx.x >> 6;
    int oy = blockIdx.x & 63;
    int tid = threadIdx.x;
    for (int t = tid; t < Pn * 27; t += 256) wsh[t] = Wdet[t];
    if (tid < Pn) bsh[tid] = bdet[tid];
    for (int t = tid; t < 3 * 3 * Wimg; t += 256) {
        int c = t / (3 * Wimg);
        int r = (t / Wimg) % 3;
        int col = t % Wimg;
        insh[c][r][col] = x[(size_t)n * 3 * HWi + (size_t)c * HWi + (oy * 4 + r) * Wimg + col];
    }
    __syncthreads();
    int ox = tid & 63;
    int wid = tid >> 6;
    float in_reg[27];
    #pragma unroll
    for (int c = 0; c < 3; c++)
        #pragma unroll
        for (int ky = 0; ky < 3; ky++)
            #pragma unroll
            for (int kx = 0; kx < 3; kx++)
                in_reg[c * 9 + ky * 3 + kx] = insh[c][ky][ox * 4 + kx];
    #pragma unroll
    for (int i = 0; i < 17; i++) {
        int p = wid + i * 4;
        const float* w = &wsh[p * 27];
        float acc = bsh[p];
        #pragma unroll
        for (int j = 0; j < 27; j++) acc += w[j] * in_reg[j];
        hm[(size_t)n * Pn * 4096 + (size_t)p * 4096 + oy * 64 + ox] = acc;
    }
}

// ---------------- softmax / soft-argmax / scores ----------------
__global__ __launch_bounds__(256) void smax_kernel(const float* __restrict__ hm,
                                                   float* __restrict__ locs,
                                                   float* __restrict__ scos) {
    int row = blockIdx.x;   // n*Pn + p
    const float4* r = (const float4*)(hm + (size_t)row * 4096);
    int tid = threadIdx.x;
    float v[16];
    #pragma unroll
    for (int j = 0; j < 4; j++) {
        float4 q = r[tid + 256 * j];
        v[4 * j + 0] = q.x; v[4 * j + 1] = q.y; v[4 * j + 2] = q.z; v[4 * j + 3] = q.w;
    }
    float m = v[0];
    #pragma unroll
    for (int i = 1; i < 16; i++) m = fmaxf(m, v[i]);
    __shared__ float redm[4];
    #pragma unroll
    for (int o = 32; o; o >>= 1) m = fmaxf(m, __shfl_xor(m, o, 64));
    int wid = tid >> 6, lane = tid & 63;
    if (lane == 0) redm[wid] = m;
    __syncthreads();
    m = fmaxf(fmaxf(redm[0], redm[1]), fmaxf(redm[2], redm[3]));
    float s = 0.f, sx = 0.f, sy = 0.f;
    #pragma unroll
    for (int j = 0; j < 4; j++) {
        #pragma unroll
        for (int q = 0; q < 4; q++) {
            int e = (tid + 256 * j) * 4 + q;
            float ev = expf(v[4 * j + q] - m);
            s += ev;
            sx += ev * (float)(e & 63);
            sy += ev * (float)(e >> 6);
        }
    }
    #pragma unroll
    for (int o = 32; o; o >>= 1) {
        s  += __shfl_xor(s, o, 64);
        sx += __shfl_xor(sx, o, 64);
        sy += __shfl_xor(sy, o, 64);
    }
    __shared__ float reds[3][4];
    if (lane == 0) { reds[0][wid] = s; reds[1][wid] = sx; reds[2][wid] = sy; }
    __syncthreads();
    if (tid == 0) {
        float S_ = reds[0][0] + reds[0][1] + reds[0][2] + reds[0][3];
        float SX = reds[1][0] + reds[1][1] + reds[1][2] + reds[1][3];
        float SY = reds[2][0] + reds[2][1] + reds[2][2] + reds[2][3];
        locs[(size_t)row * 2 + 0] = SX / S_ * 4.0f;
        locs[(size_t)row * 2 + 1] = SY / S_ * 4.0f;
        scos[row] = m;
    }
}

// ---------------- DPP wave64 sum reduction (VALU-only, ~50 cy vs ~350 cy shfl) ----------------
template <int CTRL>
__device__ inline float dpp_add(float v) {
    int t = __builtin_amdgcn_update_dpp(0, __builtin_bit_cast(int, v), CTRL, 0xF, 0xF, true);
    return v + __builtin_bit_cast(float, t);
}

// prefix-scan within 16-lane rows (row_shr 1,2,4,8), then row_bcast15 / row_bcast31;
// lane 63 holds the wave total; broadcast via readlane (SGPR).
__device__ inline float wred(float v) {
    v = dpp_add<0x111>(v);   // row_shr:1
    v = dpp_add<0x112>(v);   // row_shr:2
    v = dpp_add<0x114>(v);   // row_shr:4
    v = dpp_add<0x118>(v);   // row_shr:8
    v = dpp_add<0x142>(v);   // row_bcast:15
    v = dpp_add<0x143>(v);   // row_bcast:31
    int s = __builtin_amdgcn_readlane(__builtin_bit_cast(int, v), 63);
    return __builtin_bit_cast(float, s);
}

// ---------------- LK tracking ----------------
template <bool FLY>
__device__ inline float px_at(const float* __restrict__ im, int y, int x) {
    int i = y * Wimg + x;
    if constexpr (FLY)
        return 0.299f * im[i] + 0.587f * im[i + HWi] + 0.114f * im[i + 2 * HWi];
    else
        return im[i];
}

template <bool FLY>
__device__ inline float bilin(const float* __restrict__ im, float x, float y) {
    const float XM = (float)(Wimg - 1.001);
    const float YM = (float)(Himg - 1.001);
    x = fminf(fmaxf(x, 0.0f), XM);
    y = fminf(fmaxf(y, 0.0f), YM);
    float x0f = floorf(x), y0f = floorf(y);
    float wx = x - x0f, wy = y - y0f;
    int x0 = (int)x0f, y0 = (int)y0f;
    int x1 = min(x0 + 1, Wimg - 1), y1 = min(y0 + 1, Himg - 1);
    float v00 = px_at<FLY>(im, y0, x0);
    float v01 = px_at<FLY>(im, y0, x1);
    float v10 = px_at<FLY>(im, y1, x0);
    float v11 = px_at<FLY>(im, y1, x1);
    return (1.0f - wy) * ((1.0f - wx) * v00 + wx * v01) + wy * ((1.0f - wx) * v10 + wx * v11);
}

template <bool FLY>
__device__ inline void sample_tpl(const float* __restrict__ im, float x, float y,
                                  float& I0, float& Ix, float& Iy) {
    const float XM = (float)(Wimg - 1.001);
    const float YM = (float)(Himg - 1.001);
    x = fminf(fmaxf(x, 0.0f), XM);
    y = fminf(fmaxf(y, 0.0f), YM);
    float x0f = floorf(x), y0f = floorf(y);
    float wx = x - x0f, wy = y - y0f;
    int x0 = (int)x0f, y0 = (int)y0f;
    int x1 = min(x0 + 1, Wimg - 1), y1 = min(y0 + 1, Himg - 1);
    int xm = max(x0 - 1, 0), xp = min(x1 + 1, Wimg - 1);
    int ym = max(y0 - 1, 0), yp = min(y1 + 1, Himg - 1);
    float a_m0 = px_at<FLY>(im, ym, x0), a_m1 = px_at<FLY>(im, ym, x1);
    float a_0m = px_at<FLY>(im, y0, xm), a_00 = px_at<FLY>(im, y0, x0);
    float a_01 = px_at<FLY>(im, y0, x1), a_0p = px_at<FLY>(im, y0, xp);
    float a_1m = px_at<FLY>(im, y1, xm), a_10 = px_at<FLY>(im, y1, x0);
    float a_11 = px_at<FLY>(im, y1, x1), a_1p = px_at<FLY>(im, y1, xp);
    float a_p0 = px_at<FLY>(im, yp, x0), a_p1 = px_at<FLY>(im, yp, x1);
    float u = 1.0f - wx, t = 1.0f - wy;
    I0 = t * (u * a_00 + wx * a_01) + wy * (u * a_10 + wx * a_11);
    float gx00 = 0.5f * (a_01 - a_0m);
    float gx01 = 0.5f * (a_0p - a_00);
    float gx10 = 0.5f * (a_11 - a_1m);
    float gx11 = 0.5f * (a_1p - a_10);
    Ix = t * (u * gx00 + wx * gx01) + wy * (u * gx10 + wx * gx11);
    float gy00 = 0.5f * (a_10 - a_m0);
    float gy01 = 0.5f * (a_11 - a_m1);
    float gy10 = 0.5f * (a_p0 - a_00);
    float gy11 = 0.5f * (a_p1 - a_01);
    Iy = t * (u * gy00 + wx * gy01) + wy * (u * gy10 + wx * gy11);
}

template <bool FLY>
__device__ void lk_track(const float* __restrict__ oldI, const float* __restrict__ newI,
                         float& px, float& py, const float* dxs, const float* dys,
                         int lane) {
    float I0[5], Ixa[5], Iya[5];
    float qx[5], qy[5];
    float gxx = 0.f, gxy = 0.f, gyy = 0.f;
    #pragma unroll
    for (int j = 0; j < 5; j++) {
        int k = lane + 64 * j;
        qx[j] = px + dxs[j];
        qy[j] = py + dys[j];
        float a = 0.f, b = 0.f, c = 0.f;
        if (k < Kwin) sample_tpl<FLY>(oldI, qx[j], qy[j], a, b, c);
        I0[j] = a; Ixa[j] = b; Iya[j] = c;
        gxx += b * b; gxy += b * c; gyy += c * c;
    }
    gxx = wred(gxx); gxy = wred(gxy); gyy = wred(gyy);
    float det = gxx * gyy - gxy * gxy + 1e-6f;
    float A = gyy / det, Bv = -gxy / det, D = gxx / det;  // Ginv
    float vx = 0.f, vy = 0.f;
    for (int it = 0; it < STEPS; ++it) {
        float bx = 0.f, by = 0.f;
        #pragma unroll
        for (int j = 0; j < 5; j++) {
            int k = lane + 64 * j;
            if (k < Kwin) {
                float I1 = bilin<FLY>(newI, qx[j] + vx, qy[j] + vy);
                float err = I0[j] - I1;
                bx += err * Ixa[j];
                by += err * Iya[j];
            }
        }
        bx = wred(bx); by = wred(by);
        vx += A * bx + Bv * by;
        vy += Bv * bx + D * by;
    }
    px += vx; py += vy;
}

template <bool FLY>
__global__ __launch_bounds__(64) void lk_kernel(const float* __restrict__ grayOrIn,
                                                const float* __restrict__ locs,
                                                float* __restrict__ nextPts,
                                                float* __restrict__ fbackPts,
                                                float* __restrict__ backPts) {
    constexpr size_t FS = FLY ? (size_t)3 * HWi : (size_t)HWi;
    int g = blockIdx.x;
    int typ = g / (Bn * Pn);
    int r = g % (Bn * Pn);
    int b = r / Pn;
    int p = r % Pn;
    int lane = threadIdx.x;
    const float* G = grayOrIn + (size_t)b * Sn * FS;
    float dxs[5], dys[5];
    #pragma unroll
    for (int j = 0; j < 5; j++) {
        int k = lane + 64 * j;
        int kk = (k < Kwin) ? k : 0;
        dxs[j] = (float)(kk % 17 - 8);
        dys[j] = (float)(kk / 17 - 8);
    }
    auto LIDX = [&](int s) { return (((size_t)b * Sn + s) * Pn + p) * 2; };
    if (typ == 0) {
        float px = locs[LIDX(0)], py = locs[LIDX(0) + 1];
        if (lane == 0) { nextPts[LIDX(0)] = px; nextPts[LIDX(0) + 1] = py; }
        for (int s = 0; s < 7; s++) {
            lk_track<FLY>(G + s * FS, G + (s + 1) * FS, px, py, dxs, dys, lane);
            if (lane == 0) { nextPts[LIDX(s + 1)] = px; nextPts[LIDX(s + 1) + 1] = py; }
        }
        if (lane == 0) { fbackPts[LIDX(7)] = px; fbackPts[LIDX(7) + 1] = py; }
        for (int i = 0; i < 7; i++) {
            lk_track<FLY>(G + (7 - i) * FS, G + (6 - i) * FS, px, py, dxs, dys, lane);
            if (lane == 0) { fbackPts[LIDX(6 - i)] = px; fbackPts[LIDX(6 - i) + 1] = py; }
        }
    } else {
        float px = locs[LIDX(7)], py = locs[LIDX(7) + 1];
        if (lane == 0) { backPts[LIDX(7)] = px; backPts[LIDX(7) + 1] = py; }
        for (int i = 0; i < 7; i++) {
            lk_track<FLY>(G + (7 - i) * FS, G + (6 - i) * FS, px, py, dxs, dys, lane);
            if (lane == 0) { backPts[LIDX(6 - i)] = px; backPts[LIDX(6 - i) + 1] = py; }
        }
    }
}

// ---------------- launch ----------------
extern "C" void kernel_launch(void* const* d_in, const int* in_sizes, int n_in,
                              void* d_out, int out_size, void* d_ws, size_t ws_size,
                              hipStream_t stream) {
    const float* inputs = (const float*)d_in[0];
    const float* Wdet = (const float*)d_in[1];
    const float* bdet = (const float*)d_in[2];
    float* out = (float*)d_out;

    const size_t N_hm = (size_t)Bn * Sn * Pn * HD * WD;   // 8,912,896
    const size_t N_pts = (size_t)Bn * Sn * Pn * 2;        // 4352
    float* hm = out;
    float* locs = out + N_hm;
    float* scos = locs + N_pts;
    float* nextPts = scos + (size_t)Bn * Sn * Pn;
    float* fbackPts = nextPts + N_pts;
    float* backPts = fbackPts + N_pts;

    conv_kernel<<<NIMG * 64, 256, 0, stream>>>(inputs, Wdet, bdet, hm);
    smax_kernel<<<NIMG * Pn, 256, 0, stream>>>(hm, locs, scos);

    const size_t gray_bytes = (size_t)NIMG * HWi * sizeof(float);  // 8.4 MB
    if (ws_size >= gray_bytes) {
        float* gray = (float*)d_ws;
        gray_kernel<<<(NIMG * HWi / 4 + 255) / 256, 256, 0, stream>>>(inputs, gray);
        lk_kernel<false><<<2 * Bn * Pn, 64, 0, stream>>>(gray, locs, nextPts, fbackPts, backPts);
    } else {
        lk_kernel<true><<<2 * Bn * Pn, 64, 0, stream>>>(inputs, locs, nextPts, fbackPts, backPts);
    }
}

// Round 3
// 135.934 us; speedup vs baseline: 1.5457x; 1.3920x over previous
//
#include <hip/hip_runtime.h>
#include <math.h>

// ---------------- problem constants ----------------
namespace {
constexpr int Bn = 4, Sn = 8, Cn = 3, Himg = 256, Wimg = 256;
constexpr int Pn = 68, DS = 4, WIN = 8, STEPS = 10;
constexpr int HWi = Himg * Wimg;            // 65536
constexpr int NIMG = Bn * Sn;               // 32
constexpr int HD = Himg / DS, WD = Wimg / DS; // 64 x 64
constexpr int Kwin = (2 * WIN + 1) * (2 * WIN + 1); // 289
constexpr int NWAVE = 5;                     // waves per LK block
constexpr int TPB = NWAVE * 64;              // 320 threads, 1 sample slot per lane
}

// ---------------- gray conversion ----------------
__global__ __launch_bounds__(256) void gray_kernel(const float* __restrict__ in,
                                                   float* __restrict__ gray) {
    int idx = blockIdx.x * blockDim.x + threadIdx.x;   // float4 index
    int total = NIMG * HWi / 4;
    if (idx >= total) return;
    int img = idx / (HWi / 4);
    int off = idx % (HWi / 4);
    const float* base = in + (size_t)img * 3 * HWi;
    float4 c0 = ((const float4*)(base))[off];
    float4 c1 = ((const float4*)(base + HWi))[off];
    float4 c2 = ((const float4*)(base + 2 * HWi))[off];
    float4 g;
    g.x = 0.299f * c0.x + 0.587f * c1.x + 0.114f * c2.x;
    g.y = 0.299f * c0.y + 0.587f * c1.y + 0.114f * c2.y;
    g.z = 0.299f * c0.z + 0.587f * c1.z + 0.114f * c2.z;
    g.w = 0.299f * c0.w + 0.587f * c1.w + 0.114f * c2.w;
    ((float4*)(gray + (size_t)img * HWi))[off] = g;
}

// ---------------- detector conv (3x3, stride 4, pad 0 == SAME here) ----------------
__global__ __launch_bounds__(256) void conv_kernel(const float* __restrict__ x,
                                                   const float* __restrict__ Wdet,
                                                   const float* __restrict__ bdet,
                                                   float* __restrict__ hm) {
    __shared__ float wsh[Pn * 27];
    __shared__ float bsh[Pn];
    __shared__ float insh[3][3][Wimg];
    int n = blockIdx.x >> 6;
    int oy = blockIdx.x & 63;
    int tid = threadIdx.x;
    for (int t = tid; t < Pn * 27; t += 256) wsh[t] = Wdet[t];
    if (tid < Pn) bsh[tid] = bdet[tid];
    for (int t = tid; t < 3 * 3 * Wimg; t += 256) {
        int c = t / (3 * Wimg);
        int r = (t / Wimg) % 3;
        int col = t % Wimg;
        insh[c][r][col] = x[(size_t)n * 3 * HWi + (size_t)c * HWi + (oy * 4 + r) * Wimg + col];
    }
    __syncthreads();
    int ox = tid & 63;
    int wid = tid >> 6;
    float in_reg[27];
    #pragma unroll
    for (int c = 0; c < 3; c++)
        #pragma unroll
        for (int ky = 0; ky < 3; ky++)
            #pragma unroll
            for (int kx = 0; kx < 3; kx++)
                in_reg[c * 9 + ky * 3 + kx] = insh[c][ky][ox * 4 + kx];
    #pragma unroll
    for (int i = 0; i < 17; i++) {
        int p = wid + i * 4;
        const float* w = &wsh[p * 27];
        float acc = bsh[p];
        #pragma unroll
        for (int j = 0; j < 27; j++) acc += w[j] * in_reg[j];
        hm[(size_t)n * Pn * 4096 + (size_t)p * 4096 + oy * 64 + ox] = acc;
    }
}

// ---------------- softmax / soft-argmax / scores ----------------
__global__ __launch_bounds__(256) void smax_kernel(const float* __restrict__ hm,
                                                   float* __restrict__ locs,
                                                   float* __restrict__ scos) {
    int row = blockIdx.x;   // n*Pn + p
    const float4* r = (const float4*)(hm + (size_t)row * 4096);
    int tid = threadIdx.x;
    float v[16];
    #pragma unroll
    for (int j = 0; j < 4; j++) {
        float4 q = r[tid + 256 * j];
        v[4 * j + 0] = q.x; v[4 * j + 1] = q.y; v[4 * j + 2] = q.z; v[4 * j + 3] = q.w;
    }
    float m = v[0];
    #pragma unroll
    for (int i = 1; i < 16; i++) m = fmaxf(m, v[i]);
    __shared__ float redm[4];
    #pragma unroll
    for (int o = 32; o; o >>= 1) m = fmaxf(m, __shfl_xor(m, o, 64));
    int wid = tid >> 6, lane = tid & 63;
    if (lane == 0) redm[wid] = m;
    __syncthreads();
    m = fmaxf(fmaxf(redm[0], redm[1]), fmaxf(redm[2], redm[3]));
    float s = 0.f, sx = 0.f, sy = 0.f;
    #pragma unroll
    for (int j = 0; j < 4; j++) {
        #pragma unroll
        for (int q = 0; q < 4; q++) {
            int e = (tid + 256 * j) * 4 + q;
            float ev = expf(v[4 * j + q] - m);
            s += ev;
            sx += ev * (float)(e & 63);
            sy += ev * (float)(e >> 6);
        }
    }
    #pragma unroll
    for (int o = 32; o; o >>= 1) {
        s  += __shfl_xor(s, o, 64);
        sx += __shfl_xor(sx, o, 64);
        sy += __shfl_xor(sy, o, 64);
    }
    __shared__ float reds[3][4];
    if (lane == 0) { reds[0][wid] = s; reds[1][wid] = sx; reds[2][wid] = sy; }
    __syncthreads();
    if (tid == 0) {
        float S_ = reds[0][0] + reds[0][1] + reds[0][2] + reds[0][3];
        float SX = reds[1][0] + reds[1][1] + reds[1][2] + reds[1][3];
        float SY = reds[2][0] + reds[2][1] + reds[2][2] + reds[2][3];
        locs[(size_t)row * 2 + 0] = SX / S_ * 4.0f;
        locs[(size_t)row * 2 + 1] = SY / S_ * 4.0f;
        scos[row] = m;
    }
}

// ---------------- DPP wave64 sum reduction (VALU-only) ----------------
template <int CTRL>
__device__ inline float dpp_add(float v) {
    int t = __builtin_amdgcn_update_dpp(0, __builtin_bit_cast(int, v), CTRL, 0xF, 0xF, true);
    return v + __builtin_bit_cast(float, t);
}

// wave-wide sum, result broadcast to all lanes via readlane(63)
__device__ inline float wredw(float v) {
    v = dpp_add<0x111>(v);   // row_shr:1
    v = dpp_add<0x112>(v);   // row_shr:2
    v = dpp_add<0x114>(v);   // row_shr:4
    v = dpp_add<0x118>(v);   // row_shr:8
    v = dpp_add<0x142>(v);   // row_bcast:15
    v = dpp_add<0x143>(v);   // row_bcast:31
    int s = __builtin_amdgcn_readlane(__builtin_bit_cast(int, v), 63);
    return __builtin_bit_cast(float, s);
}

// ---------------- LK tracking ----------------
template <bool FLY>
__device__ inline float px_at(const float* __restrict__ im, int y, int x) {
    int i = y * Wimg + x;
    if constexpr (FLY)
        return 0.299f * im[i] + 0.587f * im[i + HWi] + 0.114f * im[i + 2 * HWi];
    else
        return im[i];
}

template <bool FLY>
__device__ inline float bilin(const float* __restrict__ im, float x, float y) {
    const float XM = (float)(Wimg - 1.001);
    const float YM = (float)(Himg - 1.001);
    x = fminf(fmaxf(x, 0.0f), XM);
    y = fminf(fmaxf(y, 0.0f), YM);
    float x0f = floorf(x), y0f = floorf(y);
    float wx = x - x0f, wy = y - y0f;
    int x0 = (int)x0f, y0 = (int)y0f;
    int x1 = min(x0 + 1, Wimg - 1), y1 = min(y0 + 1, Himg - 1);
    float v00 = px_at<FLY>(im, y0, x0);
    float v01 = px_at<FLY>(im, y0, x1);
    float v10 = px_at<FLY>(im, y1, x0);
    float v11 = px_at<FLY>(im, y1, x1);
    return (1.0f - wy) * ((1.0f - wx) * v00 + wx * v01) + wy * ((1.0f - wx) * v10 + wx * v11);
}

template <bool FLY>
__device__ inline void sample_tpl(const float* __restrict__ im, float x, float y,
                                  float& I0, float& Ix, float& Iy) {
    const float XM = (float)(Wimg - 1.001);
    const float YM = (float)(Himg - 1.001);
    x = fminf(fmaxf(x, 0.0f), XM);
    y = fminf(fmaxf(y, 0.0f), YM);
    float x0f = floorf(x), y0f = floorf(y);
    float wx = x - x0f, wy = y - y0f;
    int x0 = (int)x0f, y0 = (int)y0f;
    int x1 = min(x0 + 1, Wimg - 1), y1 = min(y0 + 1, Himg - 1);
    int xm = max(x0 - 1, 0), xp = min(x1 + 1, Wimg - 1);
    int ym = max(y0 - 1, 0), yp = min(y1 + 1, Himg - 1);
    float a_m0 = px_at<FLY>(im, ym, x0), a_m1 = px_at<FLY>(im, ym, x1);
    float a_0m = px_at<FLY>(im, y0, xm), a_00 = px_at<FLY>(im, y0, x0);
    float a_01 = px_at<FLY>(im, y0, x1), a_0p = px_at<FLY>(im, y0, xp);
    float a_1m = px_at<FLY>(im, y1, xm), a_10 = px_at<FLY>(im, y1, x0);
    float a_11 = px_at<FLY>(im, y1, x1), a_1p = px_at<FLY>(im, y1, xp);
    float a_p0 = px_at<FLY>(im, yp, x0), a_p1 = px_at<FLY>(im, yp, x1);
    float u = 1.0f - wx, t = 1.0f - wy;
    I0 = t * (u * a_00 + wx * a_01) + wy * (u * a_10 + wx * a_11);
    float gx00 = 0.5f * (a_01 - a_0m);
    float gx01 = 0.5f * (a_0p - a_00);
    float gx10 = 0.5f * (a_11 - a_1m);
    float gx11 = 0.5f * (a_1p - a_10);
    Ix = t * (u * gx00 + wx * gx01) + wy * (u * gx10 + wx * gx11);
    float gy00 = 0.5f * (a_10 - a_m0);
    float gy01 = 0.5f * (a_11 - a_m1);
    float gy10 = 0.5f * (a_p0 - a_00);
    float gy11 = 0.5f * (a_p1 - a_01);
    Iy = t * (u * gy00 + wx * gy01) + wy * (u * gy10 + wx * gy11);
}

// 5-wave block-level LK track step. All threads hold identical px,py on entry/exit.
// part: ping-pong LDS buffer [2][NWAVE][3]; evt: running event counter (parity picks buffer).
template <bool FLY>
__device__ void lk_track(const float* __restrict__ oldI, const float* __restrict__ newI,
                         float& px, float& py, float dx, float dy, bool act,
                         int wid, int lane, float (*part)[NWAVE][3], int& evt) {
    float qx = px + dx, qy = py + dy;
    float I0 = 0.f, Ix = 0.f, Iy = 0.f;
    if (act) sample_tpl<FLY>(oldI, qx, qy, I0, Ix, Iy);
    float gxx = wredw(Ix * Ix);
    float gxy = wredw(Ix * Iy);
    float gyy = wredw(Iy * Iy);
    {
        int eb = evt & 1; evt++;
        if (lane == 0) { part[eb][wid][0] = gxx; part[eb][wid][1] = gxy; part[eb][wid][2] = gyy; }
        __syncthreads();
        gxx = 0.f; gxy = 0.f; gyy = 0.f;
        #pragma unroll
        for (int w = 0; w < NWAVE; w++) {
            gxx += part[eb][w][0]; gxy += part[eb][w][1]; gyy += part[eb][w][2];
        }
    }
    float det = gxx * gyy - gxy * gxy + 1e-6f;
    float A = gyy / det, Bv = -gxy / det, D = gxx / det;  // Ginv
    float vx = 0.f, vy = 0.f;
    for (int it = 0; it < STEPS; ++it) {
        float bx = 0.f, by = 0.f;
        if (act) {
            float I1 = bilin<FLY>(newI, qx + vx, qy + vy);
            float err = I0 - I1;
            bx = err * Ix;
            by = err * Iy;
        }
        bx = wredw(bx); by = wredw(by);
        int eb = evt & 1; evt++;
        if (lane == 0) { part[eb][wid][0] = bx; part[eb][wid][1] = by; }
        __syncthreads();
        bx = 0.f; by = 0.f;
        #pragma unroll
        for (int w = 0; w < NWAVE; w++) { bx += part[eb][w][0]; by += part[eb][w][1]; }
        vx += A * bx + Bv * by;
        vy += Bv * bx + D * by;
    }
    px += vx; py += vy;
}

template <bool FLY>
__global__ __launch_bounds__(TPB) void lk_kernel(const float* __restrict__ grayOrIn,
                                                 const float* __restrict__ locs,
                                                 float* __restrict__ nextPts,
                                                 float* __restrict__ fbackPts,
                                                 float* __restrict__ backPts) {
    constexpr size_t FS = FLY ? (size_t)3 * HWi : (size_t)HWi;
    __shared__ float part[2][NWAVE][3];
    int g = blockIdx.x;
    int typ = g / (Bn * Pn);
    int r = g % (Bn * Pn);
    int b = r / Pn;
    int p = r % Pn;
    int tid = threadIdx.x;
    int wid = tid >> 6, lane = tid & 63;
    bool act = tid < Kwin;
    int kk = act ? tid : 0;
    float dx = (float)(kk % 17 - 8);
    float dy = (float)(kk / 17 - 8);
    const float* G = grayOrIn + (size_t)b * Sn * FS;
    int evt = 0;
    auto LIDX = [&](int s) { return (((size_t)b * Sn + s) * Pn + p) * 2; };
    if (typ == 0) {
        float px = locs[LIDX(0)], py = locs[LIDX(0) + 1];
        if (tid == 0) { nextPts[LIDX(0)] = px; nextPts[LIDX(0) + 1] = py; }
        for (int s = 0; s < 7; s++) {
            lk_track<FLY>(G + s * FS, G + (s + 1) * FS, px, py, dx, dy, act, wid, lane, part, evt);
            if (tid == 0) { nextPts[LIDX(s + 1)] = px; nextPts[LIDX(s + 1) + 1] = py; }
        }
        if (tid == 0) { fbackPts[LIDX(7)] = px; fbackPts[LIDX(7) + 1] = py; }
        for (int i = 0; i < 7; i++) {
            lk_track<FLY>(G + (7 - i) * FS, G + (6 - i) * FS, px, py, dx, dy, act, wid, lane, part, evt);
            if (tid == 0) { fbackPts[LIDX(6 - i)] = px; fbackPts[LIDX(6 - i) + 1] = py; }
        }
    } else {
        float px = locs[LIDX(7)], py = locs[LIDX(7) + 1];
        if (tid == 0) { backPts[LIDX(7)] = px; backPts[LIDX(7) + 1] = py; }
        for (int i = 0; i < 7; i++) {
            lk_track<FLY>(G + (7 - i) * FS, G + (6 - i) * FS, px, py, dx, dy, act, wid, lane, part, evt);
            if (tid == 0) { backPts[LIDX(6 - i)] = px; backPts[LIDX(6 - i) + 1] = py; }
        }
    }
}

// ---------------- launch ----------------
extern "C" void kernel_launch(void* const* d_in, const int* in_sizes, int n_in,
                              void* d_out, int out_size, void* d_ws, size_t ws_size,
                              hipStream_t stream) {
    const float* inputs = (const float*)d_in[0];
    const float* Wdet = (const float*)d_in[1];
    const float* bdet = (const float*)d_in[2];
    float* out = (float*)d_out;

    const size_t N_hm = (size_t)Bn * Sn * Pn * HD * WD;   // 8,912,896
    const size_t N_pts = (size_t)Bn * Sn * Pn * 2;        // 4352
    float* hm = out;
    float* locs = out + N_hm;
    float* scos = locs + N_pts;
    float* nextPts = scos + (size_t)Bn * Sn * Pn;
    float* fbackPts = nextPts + N_pts;
    float* backPts = fbackPts + N_pts;

    conv_kernel<<<NIMG * 64, 256, 0, stream>>>(inputs, Wdet, bdet, hm);
    smax_kernel<<<NIMG * Pn, 256, 0, stream>>>(hm, locs, scos);

    const size_t gray_bytes = (size_t)NIMG * HWi * sizeof(float);  // 8.4 MB
    if (ws_size >= gray_bytes) {
        float* gray = (float*)d_ws;
        gray_kernel<<<(NIMG * HWi / 4 + 255) / 256, 256, 0, stream>>>(inputs, gray);
        lk_kernel<false><<<2 * Bn * Pn, TPB, 0, stream>>>(gray, locs, nextPts, fbackPts, backPts);
    } else {
        lk_kernel<true><<<2 * Bn * Pn, TPB, 0, stream>>>(inputs, locs, nextPts, fbackPts, backPts);
    }
}